// Round 3
// baseline (1195.255 us; speedup 1.0000x reference)
//
#include <hip/hip_runtime.h>
#include <hip/hip_bf16.h>

typedef float f32x4 __attribute__((ext_vector_type(4)));

#define SD 8192      // S*D
#define NROWS 8192   // B*N
#define NN 4096      // N
#define DD 2048      // D

// K0: Wt[k][j] = w[j][k] * (gamma[j]+1), k in 0..23 (20 alpha cols, 4 beta cols)
__global__ void k0_prep(const float* __restrict__ gamma,
                        const float* __restrict__ daf,
                        const float* __restrict__ dbf,
                        float* __restrict__ Wt) {
    int idx = blockIdx.x * 256 + threadIdx.x;
    if (idx >= 24 * SD) return;
    int k = idx >> 13;          // /8192
    int j = idx & (SD - 1);
    float g = gamma[j] + 1.0f;
    float w = (k < 20) ? daf[j * 20 + k] : dbf[j * 4 + (k - 20)];
    Wt[(size_t)k * SD + j] = w * g;
}

// K1: per-row reductions. Grid = 128 row-groups x 8 j-slices. Block = 1024
// threads = 16 waves, 1 block/CU (96 KiB LDS). Weights for the block's
// j-slice (1024 floats x 24 k) staged in LDS ONCE, then a barrier-free main
// loop: wave owns 4 rows, lane kc owns f32x4 at kc*4 of each 256-float chunk.
// Partials per j-slice: RS[p][row][0..19]=alpha, [20..23]=beta, [24]=sumsq.
__global__ __launch_bounds__(1024, 4) void k1_reduce(const float* __restrict__ res,
                                                     const float* __restrict__ Wt,
                                                     float* __restrict__ RS) {
    __shared__ float wT[24][1024];
    const int tid = threadIdx.x;
    const int w   = tid >> 6;               // wave 0..15
    const int kc  = tid & 63;
    const int p   = blockIdx.x & 7;         // j-slice
    const int rowgrp = blockIdx.x >> 3;     // 0..127
    const int row0 = rowgrp * 64 + w * 4;   // wave's 4 rows
    const int b  = row0 >> 12;
    const int n0 = row0 & (NN - 1);
    const int js = p * 1024;
    const int s  = p >> 1;                  // slice lies in one s-plane
    const int dbase0 = (p & 1) * 1024;

    // stage this slice's weights: 6144 f32x4, 6 per thread, coalesced
#pragma unroll
    for (int i = 0; i < 6; ++i) {
        const int idx = i * 1024 + tid;     // f32x4 index
        const int k = idx >> 8, f = idx & 255;
        *(f32x4*)&wT[k][f * 4] = *(const f32x4*)(Wt + (size_t)k * SD + js + f * 4);
    }
    __syncthreads();

    float acc[4][25];
#pragma unroll
    for (int r = 0; r < 4; ++r)
#pragma unroll
        for (int k = 0; k < 25; ++k) acc[r][k] = 0.f;

#pragma unroll
    for (int c = 0; c < 4; ++c) {
        const int dbase = dbase0 + c * 256;
        f32x4 dq[4];
#pragma unroll
        for (int r = 0; r < 4; ++r) {
            const size_t g = ((size_t)(b * 4 + s) * NN + (n0 + r)) * DD + dbase + kc * 4;
            dq[r] = *(const f32x4*)(res + g);
        }
#pragma unroll
        for (int r = 0; r < 4; ++r) {
            acc[r][24] += dq[r].x * dq[r].x;
            acc[r][24] += dq[r].y * dq[r].y;
            acc[r][24] += dq[r].z * dq[r].z;
            acc[r][24] += dq[r].w * dq[r].w;
        }
#pragma unroll
        for (int k = 0; k < 24; ++k) {
            f32x4 wq = *(const f32x4*)&wT[k][c * 256 + kc * 4];
#pragma unroll
            for (int r = 0; r < 4; ++r) {
                acc[r][k] += dq[r].x * wq.x;
                acc[r][k] += dq[r].y * wq.y;
                acc[r][k] += dq[r].z * wq.z;
                acc[r][k] += dq[r].w * wq.w;
            }
        }
    }
    // butterfly reduce each accumulator across the 64 kc lanes
#pragma unroll
    for (int r = 0; r < 4; ++r)
#pragma unroll
        for (int k = 0; k < 25; ++k) {
            float v = acc[r][k];
#pragma unroll
            for (int m = 1; m < 64; m <<= 1) v += __shfl_xor(v, m);
            acc[r][k] = v;
        }
    if (kc == 0) {
#pragma unroll
        for (int r = 0; r < 4; ++r) {
            const int row = row0 + r;
#pragma unroll
            for (int k = 0; k < 25; ++k)
                RS[((size_t)p * NROWS + row) * 32 + k] = acc[r][k];
        }
    }
}

// K2: per-row alpha/sinkhorn/beta -> Coef[row][t*4+s]. 16 lanes per row
// (l = s*4+t). Sums the 8 j-slice partials from K1.
__global__ void k2_coef(const float* __restrict__ RS,
                        const float* __restrict__ sa,
                        const float* __restrict__ sb,
                        const float* __restrict__ pbs,
                        const float* __restrict__ rsc,
                        const float* __restrict__ hps,
                        float* __restrict__ Coef) {
    const int tid = threadIdx.x;
    const int g = tid >> 4, l = tid & 15;
    const int row = blockIdx.x * 16 + g;
    const int s = l >> 2, t = l & 3;
    float a_lin = 0.f, a_pre = 0.f, a_bet = 0.f, ssq = 0.f;
#pragma unroll
    for (int p = 0; p < 8; ++p) {
        const float* rr = RS + ((size_t)p * NROWS + row) * 32;
        a_lin += rr[s * 5 + t + 1];
        a_pre += rr[s * 5];
        a_bet += rr[20 + t];
        ssq   += rr[24];
    }
    const float scale = 90.50966799187809f / fmaxf(sqrtf(ssq), 1e-12f); // sqrt(8192)/norm
    float la = scale * a_lin * rsc[0] + sa[s * 5 + t + 1];
    const float a0 = scale * a_pre * pbs[0] + sa[s * 5];
    const float ap = 1.f / (1.f + __expf(-a0));
    const float bt = 2.f / (1.f + __expf(-(scale * a_bet * hps[0] + sb[t])));
#pragma unroll
    for (int it = 0; it < 20; ++it) {
        // column LSE (over s): xor 4, 8
        float m = fmaxf(la, __shfl_xor(la, 4));
        m = fmaxf(m, __shfl_xor(m, 8));
        float e = __expf(la - m);
        e += __shfl_xor(e, 4);
        e += __shfl_xor(e, 8);
        la -= m + __logf(e);
        // row LSE (over t): xor 1, 2
        m = fmaxf(la, __shfl_xor(la, 1));
        m = fmaxf(m, __shfl_xor(m, 2));
        e = __expf(la - m);
        e += __shfl_xor(e, 1);
        e += __shfl_xor(e, 2);
        la -= m + __logf(e);
    }
    Coef[(size_t)row * 16 + t * 4 + s] = ap * bt + __expf(la);
}

// K3: out[t][d] = sum_s coeff[t][s] * r[s][d]. One block per row, reverse order
// (L3 LRU friendliness), nontemporal loads/stores.
__global__ __launch_bounds__(256) void k3_mix(const float* __restrict__ res,
                                              const float* __restrict__ Coef,
                                              float* __restrict__ out) {
    const int row = (NROWS - 1) - blockIdx.x;
    const int b = row >> 12, n = row & (NN - 1);
    const int tid = threadIdx.x;
    float cf[16];
#pragma unroll
    for (int i = 0; i < 16; ++i) cf[i] = Coef[(size_t)row * 16 + i];
    f32x4 rv[4][2];
#pragma unroll
    for (int s = 0; s < 4; ++s)
#pragma unroll
        for (int p = 0; p < 2; ++p) {
            const size_t g = ((size_t)(b * 4 + s) * NN + n) * DD + p * 1024 + tid * 4;
            rv[s][p] = __builtin_nontemporal_load((const f32x4*)(res + g));
        }
#pragma unroll
    for (int t = 0; t < 4; ++t)
#pragma unroll
        for (int p = 0; p < 2; ++p) {
            f32x4 o = cf[t * 4 + 0] * rv[0][p];
            o += cf[t * 4 + 1] * rv[1][p];
            o += cf[t * 4 + 2] * rv[2][p];
            o += cf[t * 4 + 3] * rv[3][p];
            const size_t g = ((size_t)(b * 4 + t) * NN + n) * DD + p * 1024 + tid * 4;
            __builtin_nontemporal_store(o, (f32x4*)(out + g));
        }
}

extern "C" void kernel_launch(void* const* d_in, const int* in_sizes, int n_in,
                              void* d_out, int out_size, void* d_ws, size_t ws_size,
                              hipStream_t stream) {
    const float* residuals = (const float*)d_in[0];
    const float* gamma     = (const float*)d_in[1];
    const float* daf       = (const float*)d_in[2];
    const float* sa        = (const float*)d_in[3];
    const float* pbs       = (const float*)d_in[4];
    const float* rsc       = (const float*)d_in[5];
    const float* dbf       = (const float*)d_in[6];
    const float* sb        = (const float*)d_in[7];
    const float* hps       = (const float*)d_in[8];
    float* out = (float*)d_out;

    char* ws = (char*)d_ws;
    float* Wt   = (float*)ws;                       // 24*8192 f32 = 768 KiB
    float* RS   = (float*)(ws + (1 << 20));         // 8*8192*32 f32 = 8 MiB
    float* Coef = (float*)(ws + (9 << 20));         // 8192*16 f32 = 512 KiB

    k0_prep<<<768, 256, 0, stream>>>(gamma, daf, dbf, Wt);
    k1_reduce<<<1024, 1024, 0, stream>>>(residuals, Wt, RS);
    k2_coef<<<512, 256, 0, stream>>>(RS, sa, sb, pbs, rsc, hps, Coef);
    k3_mix<<<NROWS, 256, 0, stream>>>(residuals, Coef, out);
}

// Round 4
// 245.123 us; speedup vs baseline: 4.8761x; 4.8761x over previous
//
#include <hip/hip_runtime.h>
#include <hip/hip_bf16.h>

typedef float f32x4 __attribute__((ext_vector_type(4)));

#define SD 8192      // S*D
#define NROWS 8192   // B*N
#define NN 4096      // N
#define DD 2048      // D

// K0: Wt[k][j] = w[j][k] * (gamma[j]+1), k in 0..23 (20 alpha cols, 4 beta cols)
__global__ void k0_prep(const float* __restrict__ gamma,
                        const float* __restrict__ daf,
                        const float* __restrict__ dbf,
                        float* __restrict__ Wt) {
    int idx = blockIdx.x * 256 + threadIdx.x;
    if (idx >= 24 * SD) return;
    int k = idx >> 13;          // /8192
    int j = idx & (SD - 1);
    float g = gamma[j] + 1.0f;
    float w = (k < 20) ? daf[j * 20 + k] : dbf[j * 4 + (k - 20)];
    Wt[(size_t)k * SD + j] = w * g;
}

// K1: per-row reductions. Wave owns 4 rows x half the j-range. Lanes split
// (kg = lane>>4) k-columns x (jq = lane&15) j-quads: per-thread acc = 4x7 = 28
// regs (kg owns k = kg*6 .. kg*6+5; ssq computed by all, used from kg0).
// Chunk = 64 floats; 64 chunks per half. Explicit 2-deep software pipeline
// with NAMED double buffers keeps ~20 loads in flight per wave.
// Partials: RS[p][row][0..19]=alpha, [20..23]=beta, [24]=sumsq (stride 32).
__global__ __launch_bounds__(256) void k1_reduce(const float* __restrict__ res,
                                                 const float* __restrict__ Wt,
                                                 float* __restrict__ RS) {
    const int tid  = threadIdx.x;
    const int wv   = tid >> 6;
    const int lane = tid & 63;
    const int jq   = lane & 15;
    const int kg   = lane >> 4;
    const int gw   = blockIdx.x * 4 + wv;   // 0..4095
    const int p    = gw & 1;                // j-half
    const int row0 = (gw >> 1) * 4;
    const int b    = row0 >> 12;
    const int n0   = row0 & (NN - 1);
    const int jq4  = jq * 4;
    const float* __restrict__ wk = Wt + (size_t)(kg * 6) * SD;
    const int gc0 = p * 64;                 // first global chunk

    float acc[4][7];
#pragma unroll
    for (int r = 0; r < 4; ++r)
#pragma unroll
        for (int k = 0; k < 7; ++k) acc[r][k] = 0.f;

    f32x4 dA0, dA1, dA2, dA3, wA0, wA1, wA2, wA3, wA4, wA5;
    f32x4 dB0, dB1, dB2, dB3, wB0, wB1, wB2, wB3, wB4, wB5;

#define ISSUE(D0, D1, D2, D3, W0, W1, W2, W3, W4, W5, GC)                     \
    do {                                                                      \
        const int s_  = (GC) >> 5;                                            \
        const int d0_ = ((GC) & 31) << 6;                                     \
        const float* rb_ = res + ((size_t)(b * 4 + s_) * NN + n0) * DD + d0_ + jq4; \
        D0 = *(const f32x4*)(rb_);                                            \
        D1 = *(const f32x4*)(rb_ + DD);                                       \
        D2 = *(const f32x4*)(rb_ + 2 * DD);                                   \
        D3 = *(const f32x4*)(rb_ + 3 * DD);                                   \
        const float* wb_ = wk + (size_t)(GC) * 64 + jq4;                      \
        W0 = *(const f32x4*)(wb_);                                            \
        W1 = *(const f32x4*)(wb_ + SD);                                       \
        W2 = *(const f32x4*)(wb_ + 2 * SD);                                   \
        W3 = *(const f32x4*)(wb_ + 3 * SD);                                   \
        W4 = *(const f32x4*)(wb_ + 4 * SD);                                   \
        W5 = *(const f32x4*)(wb_ + 5 * SD);                                   \
    } while (0)

#define DOT4(A, K, DQ, WQ)                                                    \
    A[K] += DQ.x * WQ.x; A[K] += DQ.y * WQ.y;                                 \
    A[K] += DQ.z * WQ.z; A[K] += DQ.w * WQ.w;

#define COMPUTE(D0, D1, D2, D3, W0, W1, W2, W3, W4, W5)                       \
    do {                                                                      \
        DOT4(acc[0], 0, D0, W0) DOT4(acc[0], 1, D0, W1) DOT4(acc[0], 2, D0, W2) \
        DOT4(acc[0], 3, D0, W3) DOT4(acc[0], 4, D0, W4) DOT4(acc[0], 5, D0, W5) \
        DOT4(acc[0], 6, D0, D0)                                               \
        DOT4(acc[1], 0, D1, W0) DOT4(acc[1], 1, D1, W1) DOT4(acc[1], 2, D1, W2) \
        DOT4(acc[1], 3, D1, W3) DOT4(acc[1], 4, D1, W4) DOT4(acc[1], 5, D1, W5) \
        DOT4(acc[1], 6, D1, D1)                                               \
        DOT4(acc[2], 0, D2, W0) DOT4(acc[2], 1, D2, W1) DOT4(acc[2], 2, D2, W2) \
        DOT4(acc[2], 3, D2, W3) DOT4(acc[2], 4, D2, W4) DOT4(acc[2], 5, D2, W5) \
        DOT4(acc[2], 6, D2, D2)                                               \
        DOT4(acc[3], 0, D3, W0) DOT4(acc[3], 1, D3, W1) DOT4(acc[3], 2, D3, W2) \
        DOT4(acc[3], 3, D3, W3) DOT4(acc[3], 4, D3, W4) DOT4(acc[3], 5, D3, W5) \
        DOT4(acc[3], 6, D3, D3)                                               \
    } while (0)

#define IA ISSUE(dA0, dA1, dA2, dA3, wA0, wA1, wA2, wA3, wA4, wA5
#define IB ISSUE(dB0, dB1, dB2, dB3, wB0, wB1, wB2, wB3, wB4, wB5
#define CA COMPUTE(dA0, dA1, dA2, dA3, wA0, wA1, wA2, wA3, wA4, wA5)
#define CB COMPUTE(dB0, dB1, dB2, dB3, wB0, wB1, wB2, wB3, wB4, wB5)

    IA, gc0 + 0);
    IB, gc0 + 1);
    for (int c = 0; c < 62; c += 2) {
        CA;
        IA, gc0 + c + 2);
        CB;
        IB, gc0 + c + 3);
    }
    CA;
    CB;

    // reduce over the 16 jq lanes (stays within each kg group)
#pragma unroll
    for (int r = 0; r < 4; ++r)
#pragma unroll
        for (int k = 0; k < 7; ++k) {
            float v = acc[r][k];
            v += __shfl_xor(v, 1);
            v += __shfl_xor(v, 2);
            v += __shfl_xor(v, 4);
            v += __shfl_xor(v, 8);
            acc[r][k] = v;
        }
    if (jq == 0) {
#pragma unroll
        for (int r = 0; r < 4; ++r) {
            const size_t base = ((size_t)p * NROWS + row0 + r) * 32;
#pragma unroll
            for (int k = 0; k < 6; ++k) RS[base + kg * 6 + k] = acc[r][k];
            if (kg == 0) RS[base + 24] = acc[r][6];
        }
    }
#undef ISSUE
#undef DOT4
#undef COMPUTE
#undef IA
#undef IB
#undef CA
#undef CB
}

// K2: per-row alpha/sinkhorn/beta -> Coef[row][t*4+s]. 16 lanes per row
// (l = s*4+t). Sums the two j-half partials from K1.
__global__ void k2_coef(const float* __restrict__ RS,
                        const float* __restrict__ sa,
                        const float* __restrict__ sb,
                        const float* __restrict__ pbs,
                        const float* __restrict__ rsc,
                        const float* __restrict__ hps,
                        float* __restrict__ Coef) {
    const int tid = threadIdx.x;
    const int g = tid >> 4, l = tid & 15;
    const int row = blockIdx.x * 16 + g;
    const int s = l >> 2, t = l & 3;
    const float* r0 = RS + (size_t)row * 32;
    const float* r1 = RS + ((size_t)NROWS + row) * 32;
    const float sumsq = r0[24] + r1[24];
    const float scale = 90.50966799187809f / fmaxf(sqrtf(sumsq), 1e-12f); // sqrt(8192)/norm
    float la = scale * (r0[s * 5 + t + 1] + r1[s * 5 + t + 1]) * rsc[0] + sa[s * 5 + t + 1];
    const float a0 = scale * (r0[s * 5] + r1[s * 5]) * pbs[0] + sa[s * 5];
    const float ap = 1.f / (1.f + __expf(-a0));
    const float bt = 2.f / (1.f + __expf(-(scale * (r0[20 + t] + r1[20 + t]) * hps[0] + sb[t])));
#pragma unroll
    for (int it = 0; it < 20; ++it) {
        // column LSE (over s): xor 4, 8
        float m = fmaxf(la, __shfl_xor(la, 4));
        m = fmaxf(m, __shfl_xor(m, 8));
        float e = __expf(la - m);
        e += __shfl_xor(e, 4);
        e += __shfl_xor(e, 8);
        la -= m + __logf(e);
        // row LSE (over t): xor 1, 2
        m = fmaxf(la, __shfl_xor(la, 1));
        m = fmaxf(m, __shfl_xor(m, 2));
        e = __expf(la - m);
        e += __shfl_xor(e, 1);
        e += __shfl_xor(e, 2);
        la -= m + __logf(e);
    }
    Coef[(size_t)row * 16 + t * 4 + s] = ap * bt + __expf(la);
}

// K3: out[t][d] = sum_s coeff[t][s] * r[s][d]. One block per row, reverse order
// (L3 LRU friendliness), nontemporal stores.
__global__ __launch_bounds__(256) void k3_mix(const float* __restrict__ res,
                                              const float* __restrict__ Coef,
                                              float* __restrict__ out) {
    const int row = (NROWS - 1) - blockIdx.x;
    const int b = row >> 12, n = row & (NN - 1);
    const int tid = threadIdx.x;
    float cf[16];
#pragma unroll
    for (int i = 0; i < 16; ++i) cf[i] = Coef[(size_t)row * 16 + i];
    f32x4 rv[4][2];
#pragma unroll
    for (int s = 0; s < 4; ++s)
#pragma unroll
        for (int p = 0; p < 2; ++p) {
            const size_t g = ((size_t)(b * 4 + s) * NN + n) * DD + p * 1024 + tid * 4;
            rv[s][p] = __builtin_nontemporal_load((const f32x4*)(res + g));
        }
#pragma unroll
    for (int t = 0; t < 4; ++t)
#pragma unroll
        for (int p = 0; p < 2; ++p) {
            f32x4 o = cf[t * 4 + 0] * rv[0][p];
            o += cf[t * 4 + 1] * rv[1][p];
            o += cf[t * 4 + 2] * rv[2][p];
            o += cf[t * 4 + 3] * rv[3][p];
            const size_t g = ((size_t)(b * 4 + t) * NN + n) * DD + p * 1024 + tid * 4;
            __builtin_nontemporal_store(o, (f32x4*)(out + g));
        }
}

extern "C" void kernel_launch(void* const* d_in, const int* in_sizes, int n_in,
                              void* d_out, int out_size, void* d_ws, size_t ws_size,
                              hipStream_t stream) {
    const float* residuals = (const float*)d_in[0];
    const float* gamma     = (const float*)d_in[1];
    const float* daf       = (const float*)d_in[2];
    const float* sa        = (const float*)d_in[3];
    const float* pbs       = (const float*)d_in[4];
    const float* rsc       = (const float*)d_in[5];
    const float* dbf       = (const float*)d_in[6];
    const float* sb        = (const float*)d_in[7];
    const float* hps       = (const float*)d_in[8];
    float* out = (float*)d_out;

    char* ws = (char*)d_ws;
    float* Wt   = (float*)ws;                       // 24*8192 f32 = 768 KiB
    float* RS   = (float*)(ws + (1 << 20));         // 2*8192*32 f32 = 2 MiB
    float* Coef = (float*)(ws + (3 << 20));         // 8192*16 f32 = 512 KiB

    k0_prep<<<768, 256, 0, stream>>>(gamma, daf, dbf, Wt);
    k1_reduce<<<1024, 256, 0, stream>>>(residuals, Wt, RS);
    k2_coef<<<512, 256, 0, stream>>>(RS, sa, sb, pbs, rsc, hps, Coef);
    k3_mix<<<NROWS, 256, 0, stream>>>(residuals, Coef, out);
}

// Round 5
// 173.834 us; speedup vs baseline: 6.8758x; 1.4101x over previous
//
#include <hip/hip_runtime.h>
#include <hip/hip_bf16.h>

typedef float f32x4 __attribute__((ext_vector_type(4)));

#define SD 8192      // S*D
#define NROWS 8192   // B*N
#define NN 4096      // N
#define DD 2048      // D

// K0: Wt[k][j] = w[j][k] * (gamma[j]+1), k in 0..23 (20 alpha cols, 4 beta cols)
__global__ void k0_prep(const float* __restrict__ gamma,
                        const float* __restrict__ daf,
                        const float* __restrict__ dbf,
                        float* __restrict__ Wt) {
    int idx = blockIdx.x * 256 + threadIdx.x;
    if (idx >= 24 * SD) return;
    int k = idx >> 13;          // /8192
    int j = idx & (SD - 1);
    float g = gamma[j] + 1.0f;
    float w = (k < 20) ? daf[j * 20 + k] : dbf[j * 4 + (k - 20)];
    Wt[(size_t)k * SD + j] = w * g;
}

// K1: per-row reductions via async global->LDS staging (fire-and-forget).
// Block = 256 thr, 16 rows, full SD in 32 chunks of 256 floats, double-buffered.
// LDS/buffer: 16x256 data + 24x256 weights = 40 KiB; x2 = 80 KiB -> 2 blocks/CU.
// Stage: wave wv issues its 4 data rows + its 6 weight rows (10 x global_load_lds
// width-16, dest = wave-uniform base + lane*16, source = base + lane*16).
// Compute: lane = (kg = lane>>4, jq = lane&15); wave wv owns rows wv*4..+3;
// kg owns k = kg*6..+5; thread covers quads jq+16q, q=0..3.
// acc = 4 rows x 6 k + 4 ssq = 28 regs. Butterfly over jq (xor 1,2,4,8).
// Bank analysis: data reads are 16 unique 16B addrs x4 kg-broadcast (free);
// weight reads spread 8/bank = the structural wave64-b128 floor (uniform). No swizzle.
__global__ __launch_bounds__(256) void k1_reduce(const float* __restrict__ res,
                                                 const float* __restrict__ Wt,
                                                 float* __restrict__ RS) {
    __shared__ float lds[2][10240];     // [buf][0..4095]=data, [4096..10239]=weights
    const int tid  = threadIdx.x;
    const int wv   = tid >> 6;
    const int lane = tid & 63;
    const int jq   = lane & 15;
    const int kg   = lane >> 4;
    const int row0 = blockIdx.x * 16;
    const int b    = row0 >> 12;
    const int n0   = row0 & (NN - 1);

    float acc[4][6];
    float ssq[4];
#pragma unroll
    for (int i = 0; i < 4; ++i) {
        ssq[i] = 0.f;
#pragma unroll
        for (int k = 0; k < 6; ++k) acc[i][k] = 0.f;
    }

    auto stage = [&](int buf, int c) {
        const int s = c >> 3;
        const int dbase = (c & 7) * 256;
#pragma unroll
        for (int i = 0; i < 4; ++i) {
            const int r = wv * 4 + i;
            const float* g = res + ((size_t)(b * 4 + s) * NN + (n0 + r)) * DD + dbase + lane * 4;
            float* l = &lds[buf][r * 256];
            __builtin_amdgcn_global_load_lds((const __attribute__((address_space(1))) void*)g,
                                             (__attribute__((address_space(3))) void*)l,
                                             16, 0, 0);
        }
#pragma unroll
        for (int kk = 0; kk < 6; ++kk) {
            const int k = wv * 6 + kk;
            const float* g = Wt + (size_t)k * SD + c * 256 + lane * 4;
            float* l = &lds[buf][4096 + k * 256];
            __builtin_amdgcn_global_load_lds((const __attribute__((address_space(1))) void*)g,
                                             (__attribute__((address_space(3))) void*)l,
                                             16, 0, 0);
        }
    };

    auto compute = [&](int buf) {
        const float* dT = &lds[buf][0];
        const float* wT = &lds[buf][4096];
#pragma unroll
        for (int q = 0; q < 4; ++q) {
            const int fq = (jq + 16 * q) * 4;
            f32x4 d[4];
#pragma unroll
            for (int i = 0; i < 4; ++i)
                d[i] = *(const f32x4*)&dT[(wv * 4 + i) * 256 + fq];
#pragma unroll
            for (int i = 0; i < 4; ++i) {
                ssq[i] += d[i].x * d[i].x;
                ssq[i] += d[i].y * d[i].y;
                ssq[i] += d[i].z * d[i].z;
                ssq[i] += d[i].w * d[i].w;
            }
#pragma unroll
            for (int kk = 0; kk < 6; ++kk) {
                const f32x4 w = *(const f32x4*)&wT[(kg * 6 + kk) * 256 + fq];
#pragma unroll
                for (int i = 0; i < 4; ++i) {
                    acc[i][kk] += d[i].x * w.x;
                    acc[i][kk] += d[i].y * w.y;
                    acc[i][kk] += d[i].z * w.z;
                    acc[i][kk] += d[i].w * w.w;
                }
            }
        }
    };

    stage(0, 0);
    for (int c = 0; c < 32; ++c) {
        if (c + 1 < 32) stage((c + 1) & 1, c + 1);
        __syncthreads();                // drains vmcnt -> buf[c&1] fully staged
        compute(c & 1);
        __syncthreads();                // done reading before re-stage
    }

    // reduce over the 16 jq lanes (xor 1,2,4,8 stays within each kg group)
#pragma unroll
    for (int i = 0; i < 4; ++i) {
#pragma unroll
        for (int kk = 0; kk < 6; ++kk) {
            float v = acc[i][kk];
            v += __shfl_xor(v, 1);
            v += __shfl_xor(v, 2);
            v += __shfl_xor(v, 4);
            v += __shfl_xor(v, 8);
            acc[i][kk] = v;
        }
        float v = ssq[i];
        v += __shfl_xor(v, 1);
        v += __shfl_xor(v, 2);
        v += __shfl_xor(v, 4);
        v += __shfl_xor(v, 8);
        ssq[i] = v;
    }
    if (jq == 0) {
#pragma unroll
        for (int i = 0; i < 4; ++i) {
            const size_t base = (size_t)(row0 + wv * 4 + i) * 32;
#pragma unroll
            for (int kk = 0; kk < 6; ++kk) RS[base + kg * 6 + kk] = acc[i][kk];
            if (kg == 0) RS[base + 24] = ssq[i];
        }
    }
}

// K2: per-row alpha/sinkhorn/beta -> Coef[row][t*4+s]. 16 lanes per row (l = s*4+t).
__global__ void k2_coef(const float* __restrict__ RS,
                        const float* __restrict__ sa,
                        const float* __restrict__ sb,
                        const float* __restrict__ pbs,
                        const float* __restrict__ rsc,
                        const float* __restrict__ hps,
                        float* __restrict__ Coef) {
    const int tid = threadIdx.x;
    const int g = tid >> 4, l = tid & 15;
    const int row = blockIdx.x * 16 + g;
    const int s = l >> 2, t = l & 3;
    const float* rr = RS + (size_t)row * 32;
    const float scale = 90.50966799187809f / fmaxf(sqrtf(rr[24]), 1e-12f); // sqrt(8192)/norm
    float la = scale * rr[s * 5 + t + 1] * rsc[0] + sa[s * 5 + t + 1];
    const float a0 = scale * rr[s * 5] * pbs[0] + sa[s * 5];
    const float ap = 1.f / (1.f + __expf(-a0));
    const float bt = 2.f / (1.f + __expf(-(scale * rr[20 + t] * hps[0] + sb[t])));
#pragma unroll
    for (int it = 0; it < 20; ++it) {
        // column LSE (over s): xor 4, 8
        float m = fmaxf(la, __shfl_xor(la, 4));
        m = fmaxf(m, __shfl_xor(m, 8));
        float e = __expf(la - m);
        e += __shfl_xor(e, 4);
        e += __shfl_xor(e, 8);
        la -= m + __logf(e);
        // row LSE (over t): xor 1, 2
        m = fmaxf(la, __shfl_xor(la, 1));
        m = fmaxf(m, __shfl_xor(m, 2));
        e = __expf(la - m);
        e += __shfl_xor(e, 1);
        e += __shfl_xor(e, 2);
        la -= m + __logf(e);
    }
    Coef[(size_t)row * 16 + t * 4 + s] = ap * bt + __expf(la);
}

// K3: out[t][d] = sum_s coeff[t][s] * r[s][d]. One block per row, reverse order
// (L3 LRU friendliness), nontemporal stores.
__global__ __launch_bounds__(256) void k3_mix(const float* __restrict__ res,
                                              const float* __restrict__ Coef,
                                              float* __restrict__ out) {
    const int row = (NROWS - 1) - blockIdx.x;
    const int b = row >> 12, n = row & (NN - 1);
    const int tid = threadIdx.x;
    float cf[16];
#pragma unroll
    for (int i = 0; i < 16; ++i) cf[i] = Coef[(size_t)row * 16 + i];
    f32x4 rv[4][2];
#pragma unroll
    for (int s = 0; s < 4; ++s)
#pragma unroll
        for (int p = 0; p < 2; ++p) {
            const size_t g = ((size_t)(b * 4 + s) * NN + n) * DD + p * 1024 + tid * 4;
            rv[s][p] = __builtin_nontemporal_load((const f32x4*)(res + g));
        }
#pragma unroll
    for (int t = 0; t < 4; ++t)
#pragma unroll
        for (int p = 0; p < 2; ++p) {
            f32x4 o = cf[t * 4 + 0] * rv[0][p];
            o += cf[t * 4 + 1] * rv[1][p];
            o += cf[t * 4 + 2] * rv[2][p];
            o += cf[t * 4 + 3] * rv[3][p];
            const size_t g = ((size_t)(b * 4 + t) * NN + n) * DD + p * 1024 + tid * 4;
            __builtin_nontemporal_store(o, (f32x4*)(out + g));
        }
}

extern "C" void kernel_launch(void* const* d_in, const int* in_sizes, int n_in,
                              void* d_out, int out_size, void* d_ws, size_t ws_size,
                              hipStream_t stream) {
    const float* residuals = (const float*)d_in[0];
    const float* gamma     = (const float*)d_in[1];
    const float* daf       = (const float*)d_in[2];
    const float* sa        = (const float*)d_in[3];
    const float* pbs       = (const float*)d_in[4];
    const float* rsc       = (const float*)d_in[5];
    const float* dbf       = (const float*)d_in[6];
    const float* sb        = (const float*)d_in[7];
    const float* hps       = (const float*)d_in[8];
    float* out = (float*)d_out;

    char* ws = (char*)d_ws;
    float* Wt   = (float*)ws;                       // 24*8192 f32 = 768 KiB
    float* RS   = (float*)(ws + (1 << 20));         // 8192*32 f32 = 1 MiB
    float* Coef = (float*)(ws + (2 << 20));         // 8192*16 f32 = 512 KiB

    k0_prep<<<768, 256, 0, stream>>>(gamma, daf, dbf, Wt);
    k1_reduce<<<512, 256, 0, stream>>>(residuals, Wt, RS);
    k2_coef<<<512, 256, 0, stream>>>(RS, sa, sb, pbs, rsc, hps, Coef);
    k3_mix<<<NROWS, 256, 0, stream>>>(residuals, Coef, out);
}

// Round 6
// 168.325 us; speedup vs baseline: 7.1009x; 1.0327x over previous
//
#include <hip/hip_runtime.h>
#include <hip/hip_bf16.h>

typedef float f32x4 __attribute__((ext_vector_type(4)));

#define SD 8192      // S*D
#define NROWS 8192   // B*N
#define NN 4096      // N
#define DD 2048      // D

// K0: Wt[k][j] = w[j][k] * (gamma[j]+1), k in 0..23 (20 alpha cols, 4 beta cols)
__global__ void k0_prep(const float* __restrict__ gamma,
                        const float* __restrict__ daf,
                        const float* __restrict__ dbf,
                        float* __restrict__ Wt) {
    int idx = blockIdx.x * 256 + threadIdx.x;
    if (idx >= 24 * SD) return;
    int k = idx >> 13;          // /8192
    int j = idx & (SD - 1);
    float g = gamma[j] + 1.0f;
    float w = (k < 20) ? daf[j * 20 + k] : dbf[j * 4 + (k - 20)];
    Wt[(size_t)k * SD + j] = w * g;
}

// K1: per-row reductions via async global->LDS staging with COUNTED vmcnt
// (T3/T4): the next chunk's 10 global_load_lds stay in flight across the
// barrier; we wait only for the current buffer (vmcnt(10): each wave issues
// exactly 10 loads per stage, so all-but-newest-10 == current chunk landed;
// per-wave wait + barrier => all waves' stages landed).
// Block = 256 thr, 16 rows, 32 chunks of 256 floats, double-buffered LDS
// (2 x 40 KiB = 80 KiB -> 2 blocks/CU).
// Compute: lane = (kg = lane>>4, jq = lane&15); wave wv owns rows wv*4..+3;
// kg owns k = kg*6..+5; thread covers quads jq+16q, q=0..3.
__global__ __launch_bounds__(256) void k1_reduce(const float* __restrict__ res,
                                                 const float* __restrict__ Wt,
                                                 float* __restrict__ RS) {
    __shared__ float lds[2][10240];     // [buf][0..4095]=data, [4096..10239]=weights
    const int tid  = threadIdx.x;
    const int wv   = tid >> 6;
    const int lane = tid & 63;
    const int jq   = lane & 15;
    const int kg   = lane >> 4;
    const int row0 = blockIdx.x * 16;
    const int b    = row0 >> 12;
    const int n0   = row0 & (NN - 1);

    float acc[4][6];
    float ssq[4];
#pragma unroll
    for (int i = 0; i < 4; ++i) {
        ssq[i] = 0.f;
#pragma unroll
        for (int k = 0; k < 6; ++k) acc[i][k] = 0.f;
    }

    auto stage = [&](int buf, int c) {
        const int s = c >> 3;
        const int dbase = (c & 7) * 256;
#pragma unroll
        for (int i = 0; i < 4; ++i) {
            const int r = wv * 4 + i;
            const float* g = res + ((size_t)(b * 4 + s) * NN + (n0 + r)) * DD + dbase + lane * 4;
            float* l = &lds[buf][r * 256];
            __builtin_amdgcn_global_load_lds((const __attribute__((address_space(1))) void*)g,
                                             (__attribute__((address_space(3))) void*)l,
                                             16, 0, 0);
        }
#pragma unroll
        for (int kk = 0; kk < 6; ++kk) {
            const int k = wv * 6 + kk;
            const float* g = Wt + (size_t)k * SD + c * 256 + lane * 4;
            float* l = &lds[buf][4096 + k * 256];
            __builtin_amdgcn_global_load_lds((const __attribute__((address_space(1))) void*)g,
                                             (__attribute__((address_space(3))) void*)l,
                                             16, 0, 0);
        }
    };

    auto compute = [&](int buf) {
        const float* dT = &lds[buf][0];
        const float* wT = &lds[buf][4096];
#pragma unroll
        for (int q = 0; q < 4; ++q) {
            const int fq = (jq + 16 * q) * 4;
            f32x4 d[4];
#pragma unroll
            for (int i = 0; i < 4; ++i)
                d[i] = *(const f32x4*)&dT[(wv * 4 + i) * 256 + fq];
#pragma unroll
            for (int i = 0; i < 4; ++i) {
                ssq[i] += d[i].x * d[i].x;
                ssq[i] += d[i].y * d[i].y;
                ssq[i] += d[i].z * d[i].z;
                ssq[i] += d[i].w * d[i].w;
            }
#pragma unroll
            for (int kk = 0; kk < 6; ++kk) {
                const f32x4 w = *(const f32x4*)&wT[(kg * 6 + kk) * 256 + fq];
#pragma unroll
                for (int i = 0; i < 4; ++i) {
                    acc[i][kk] += d[i].x * w.x;
                    acc[i][kk] += d[i].y * w.y;
                    acc[i][kk] += d[i].z * w.z;
                    acc[i][kk] += d[i].w * w.w;
                }
            }
        }
    };

    stage(0, 0);
    stage(1, 1);
    for (int c = 0; c < 32; ++c) {
        if (c < 30) {
            // current buffer's 10 loads done; next buffer's 10 stay in flight
            asm volatile("s_waitcnt vmcnt(10)" ::: "memory");
        } else {
            asm volatile("s_waitcnt vmcnt(0)" ::: "memory");
        }
        __builtin_amdgcn_sched_barrier(0);
        __builtin_amdgcn_s_barrier();
        compute(c & 1);
        __builtin_amdgcn_s_barrier();   // all waves done reading buf before re-stage
        if (c + 2 < 32) stage(c & 1, c + 2);
    }

    // reduce over the 16 jq lanes (xor 1,2,4,8 stays within each kg group)
#pragma unroll
    for (int i = 0; i < 4; ++i) {
#pragma unroll
        for (int kk = 0; kk < 6; ++kk) {
            float v = acc[i][kk];
            v += __shfl_xor(v, 1);
            v += __shfl_xor(v, 2);
            v += __shfl_xor(v, 4);
            v += __shfl_xor(v, 8);
            acc[i][kk] = v;
        }
        float v = ssq[i];
        v += __shfl_xor(v, 1);
        v += __shfl_xor(v, 2);
        v += __shfl_xor(v, 4);
        v += __shfl_xor(v, 8);
        ssq[i] = v;
    }
    if (jq == 0) {
#pragma unroll
        for (int i = 0; i < 4; ++i) {
            const size_t base = (size_t)(row0 + wv * 4 + i) * 32;
#pragma unroll
            for (int kk = 0; kk < 6; ++kk) RS[base + kg * 6 + kk] = acc[i][kk];
            if (kg == 0) RS[base + 24] = ssq[i];
        }
    }
}

// K2: per-row alpha/sinkhorn/beta -> Coef[row][t*4+s]. 16 lanes per row (l = s*4+t).
__global__ void k2_coef(const float* __restrict__ RS,
                        const float* __restrict__ sa,
                        const float* __restrict__ sb,
                        const float* __restrict__ pbs,
                        const float* __restrict__ rsc,
                        const float* __restrict__ hps,
                        float* __restrict__ Coef) {
    const int tid = threadIdx.x;
    const int g = tid >> 4, l = tid & 15;
    const int row = blockIdx.x * 16 + g;
    const int s = l >> 2, t = l & 3;
    const float* rr = RS + (size_t)row * 32;
    const float scale = 90.50966799187809f / fmaxf(sqrtf(rr[24]), 1e-12f); // sqrt(8192)/norm
    float la = scale * rr[s * 5 + t + 1] * rsc[0] + sa[s * 5 + t + 1];
    const float a0 = scale * rr[s * 5] * pbs[0] + sa[s * 5];
    const float ap = 1.f / (1.f + __expf(-a0));
    const float bt = 2.f / (1.f + __expf(-(scale * rr[20 + t] * hps[0] + sb[t])));
#pragma unroll
    for (int it = 0; it < 20; ++it) {
        // column LSE (over s): xor 4, 8
        float m = fmaxf(la, __shfl_xor(la, 4));
        m = fmaxf(m, __shfl_xor(m, 8));
        float e = __expf(la - m);
        e += __shfl_xor(e, 4);
        e += __shfl_xor(e, 8);
        la -= m + __logf(e);
        // row LSE (over t): xor 1, 2
        m = fmaxf(la, __shfl_xor(la, 1));
        m = fmaxf(m, __shfl_xor(m, 2));
        e = __expf(la - m);
        e += __shfl_xor(e, 1);
        e += __shfl_xor(e, 2);
        la -= m + __logf(e);
    }
    Coef[(size_t)row * 16 + t * 4 + s] = ap * bt + __expf(la);
}

// K3: out[t][d] = sum_s coeff[t][s] * r[s][d]. One block per row, reverse order
// (L3 LRU friendliness), nontemporal stores.
__global__ __launch_bounds__(256) void k3_mix(const float* __restrict__ res,
                                              const float* __restrict__ Coef,
                                              float* __restrict__ out) {
    const int row = (NROWS - 1) - blockIdx.x;
    const int b = row >> 12, n = row & (NN - 1);
    const int tid = threadIdx.x;
    float cf[16];
#pragma unroll
    for (int i = 0; i < 16; ++i) cf[i] = Coef[(size_t)row * 16 + i];
    f32x4 rv[4][2];
#pragma unroll
    for (int s = 0; s < 4; ++s)
#pragma unroll
        for (int p = 0; p < 2; ++p) {
            const size_t g = ((size_t)(b * 4 + s) * NN + n) * DD + p * 1024 + tid * 4;
            rv[s][p] = __builtin_nontemporal_load((const f32x4*)(res + g));
        }
#pragma unroll
    for (int t = 0; t < 4; ++t)
#pragma unroll
        for (int p = 0; p < 2; ++p) {
            f32x4 o = cf[t * 4 + 0] * rv[0][p];
            o += cf[t * 4 + 1] * rv[1][p];
            o += cf[t * 4 + 2] * rv[2][p];
            o += cf[t * 4 + 3] * rv[3][p];
            const size_t g = ((size_t)(b * 4 + t) * NN + n) * DD + p * 1024 + tid * 4;
            __builtin_nontemporal_store(o, (f32x4*)(out + g));
        }
}

extern "C" void kernel_launch(void* const* d_in, const int* in_sizes, int n_in,
                              void* d_out, int out_size, void* d_ws, size_t ws_size,
                              hipStream_t stream) {
    const float* residuals = (const float*)d_in[0];
    const float* gamma     = (const float*)d_in[1];
    const float* daf       = (const float*)d_in[2];
    const float* sa        = (const float*)d_in[3];
    const float* pbs       = (const float*)d_in[4];
    const float* rsc       = (const float*)d_in[5];
    const float* dbf       = (const float*)d_in[6];
    const float* sb        = (const float*)d_in[7];
    const float* hps       = (const float*)d_in[8];
    float* out = (float*)d_out;

    char* ws = (char*)d_ws;
    float* Wt   = (float*)ws;                       // 24*8192 f32 = 768 KiB
    float* RS   = (float*)(ws + (1 << 20));         // 8192*32 f32 = 1 MiB
    float* Coef = (float*)(ws + (2 << 20));         // 8192*16 f32 = 512 KiB

    k0_prep<<<768, 256, 0, stream>>>(gamma, daf, dbf, Wt);
    k1_reduce<<<512, 256, 0, stream>>>(residuals, Wt, RS);
    k2_coef<<<512, 256, 0, stream>>>(RS, sa, sb, pbs, rsc, hps, Coef);
    k3_mix<<<NROWS, 256, 0, stream>>>(residuals, Coef, out);
}